// Round 3
// baseline (129.556 us; speedup 1.0000x reference)
//
#include <hip/hip_runtime.h>
#include <math.h>

#define N_   32
#define C_   512
#define P_   1024
#define KG_  10
#define KV_  8
#define PT_  16            // p rows per LDS tile
#define TILES_ 4           // tiles per block -> 64 p per block
#define PB_  (PT_ * TILES_)
#define NBLK_P 16          // P_ / PB_
#define XS_  516           // xt row stride (mult of 4 for b128 align; 516%32=4 -> conflict-free reads)

// LDS-only barrier: does NOT drain vmcnt, so register-prefetch global loads
// stay in flight across it (HIP __syncthreads would emit s_waitcnt vmcnt(0)).
// All cross-thread traffic in this kernel is LDS, so lgkmcnt(0) suffices.
__device__ __forceinline__ void bar_lds() {
  asm volatile("s_waitcnt lgkmcnt(0)\n\ts_barrier" ::: "memory");
}

// ---------------------------------------------------------------------------
// Fused kernel: per (n, 64-p chunk). Register-prefetch pipelines the x stream
// across tiles; w lives in LDS (keeps vmcnt FIFO private to the prefetch).
// Grid: N*16 = 512 blocks of 256 threads.
// ---------------------------------------------------------------------------
__global__ __launch_bounds__(256) void vlad_fused(
    const float* __restrict__ x, const float* __restrict__ w,
    const float* __restrict__ bias,
    float* __restrict__ part_ax, float* __restrict__ asum_part) {
  __shared__ __align__(16) float xt[PT_ * XS_];    // 33024 B  [p][c]
  __shared__ __align__(16) float wt[KG_ * C_];     // 20480 B  [k][c]
  __shared__ __align__(16) float part[160 * 12];   //  7680 B  8 cols used
  __shared__ __align__(16) float lg[PT_ * KG_];    //   640 B
  __shared__ __align__(16) float a_l[PT_ * KV_];   //   512 B   total 62336 B

  const int t    = threadIdx.x;
  const int lane = t & 63;
  const int wv   = t >> 6;
  const int n    = blockIdx.x >> 4;
  const int pb   = blockIdx.x & 15;
  const int gp0  = pb * PB_;

  const float* xn = x + (size_t)n * C_ * P_;

  // ---- prologue: stage w -> LDS (vmcnt FIFO: w first, then tile-0 pf) ----
  float4 wstage[5];
#pragma unroll
  for (int j = 0; j < 5; ++j)
    wstage[j] = *reinterpret_cast<const float4*>(w + (j * 256 + t) * 4);

  float4 pf[8];
  {
    const int c  = t >> 2;            // per-thread transpose coords (fixed)
    const int p4 = (t & 3) * 4;
#pragma unroll
    for (int j = 0; j < 8; ++j)
      pf[j] = *reinterpret_cast<const float4*>(
          xn + (size_t)(j * 64 + c) * P_ + gp0 + p4);
  }
#pragma unroll
  for (int j = 0; j < 5; ++j)
    *reinterpret_cast<float4*>(&wt[(j * 256 + t) * 4]) = wstage[j];

  float acc2[2][KV_];
#pragma unroll
  for (int k = 0; k < KV_; ++k) { acc2[0][k] = 0.f; acc2[1][k] = 0.f; }
  float asum[KV_];
#pragma unroll
  for (int k = 0; k < KV_; ++k) asum[k] = 0.f;

  const int cT  = t >> 2;             // transpose-store coords
  const int p4T = (t & 3) * 4;

  for (int tt = 0; tt < TILES_; ++tt) {
    if (tt) bar_lds();                // previous tile's xt readers done

    // ---- write prefetched tile into xt (transpose scatter) ----
#pragma unroll
    for (int j = 0; j < 8; ++j) {
      const int c = j * 64 + cT;
      xt[(p4T + 0) * XS_ + c] = pf[j].x;
      xt[(p4T + 1) * XS_ + c] = pf[j].y;
      xt[(p4T + 2) * XS_ + c] = pf[j].z;
      xt[(p4T + 3) * XS_ + c] = pf[j].w;
    }
    bar_lds();                        // xt (and, on tt==0, wt) ready

    // ---- issue next tile's global loads NOW; land during compute ----
    if (tt + 1 < TILES_) {
      const int gp = gp0 + (tt + 1) * PT_;
#pragma unroll
      for (int j = 0; j < 8; ++j)
        pf[j] = *reinterpret_cast<const float4*>(
            xn + (size_t)(j * 64 + cT) * P_ + gp + p4T);
    }

    // ---- P2: logits. wave wv owns p rows wv*4..wv*4+3; lane <-> 4 c's ----
    float acc[4][KG_];
#pragma unroll
    for (int pj = 0; pj < 4; ++pj)
#pragma unroll
      for (int k = 0; k < KG_; ++k) acc[pj][k] = 0.f;

#pragma unroll
    for (int half = 0; half < 2; ++half) {
      const int c0 = half * 256 + lane * 4;
      float4 wk[KG_];
#pragma unroll
      for (int k = 0; k < KG_; ++k)
        wk[k] = *reinterpret_cast<const float4*>(&wt[k * C_ + c0]);
#pragma unroll
      for (int pj = 0; pj < 4; ++pj) {
        const float4 x4 =
            *reinterpret_cast<const float4*>(&xt[(wv * 4 + pj) * XS_ + c0]);
#pragma unroll
        for (int k = 0; k < KG_; ++k)
          acc[pj][k] += x4.x * wk[k].x + x4.y * wk[k].y
                      + x4.z * wk[k].z + x4.w * wk[k].w;
      }
    }
    // reduce over lanes xor {1,2,4} -> 8 partial columns
#pragma unroll
    for (int pj = 0; pj < 4; ++pj) {
#pragma unroll
      for (int k = 0; k < KG_; ++k) {
        float v = acc[pj][k];
        v += __shfl_xor(v, 1, 64);
        v += __shfl_xor(v, 2, 64);
        v += __shfl_xor(v, 4, 64);
        if ((lane & 7) == 0)
          part[(wv * 40 + pj * 10 + k) * 12 + (lane >> 3)] = v;
      }
    }
    bar_lds();

    if (t < 160) {
      const float* row = &part[t * 12];
      const float4 s0 = *reinterpret_cast<const float4*>(row);
      const float4 s1 = *reinterpret_cast<const float4*>(row + 4);
      const float s = ((s0.x + s0.y) + (s0.z + s0.w)) +
                      ((s1.x + s1.y) + (s1.z + s1.w));
      const int k = t % 10;
      const int p = (t / 40) * 4 + (t % 40) / 10;
      lg[p * KG_ + k] = s + bias[k];
    }
    bar_lds();

    if (t < PT_) {
      float l[KG_];
      float m = -1e30f;
#pragma unroll
      for (int k = 0; k < KG_; ++k) {
        l[k] = lg[t * KG_ + k];
        m = fmaxf(m, l[k]);
      }
      float sum = 0.f;
#pragma unroll
      for (int k = 0; k < KG_; ++k) { l[k] = __expf(l[k] - m); sum += l[k]; }
      const float inv = 1.f / sum;
#pragma unroll
      for (int k = 0; k < KV_; ++k) {
        const float a = l[k] * inv;
        a_l[t * KV_ + k] = a;
        float s = a;                   // sum over the 16 active lanes (= 16 p)
        s += __shfl_xor(s, 1, 64);
        s += __shfl_xor(s, 2, 64);
        s += __shfl_xor(s, 4, 64);
        s += __shfl_xor(s, 8, 64);
        asum[k] += s;
      }
    }
    bar_lds();

    // ---- P3: ax partial accumulation; lane <-> c (t and t+256) ----
#pragma unroll 4
    for (int p = 0; p < PT_; ++p) {
      const float4 a0 = *reinterpret_cast<const float4*>(&a_l[p * KV_]);
      const float4 a1 = *reinterpret_cast<const float4*>(&a_l[p * KV_ + 4]);
      const float x0 = xt[p * XS_ + t];
      const float x1 = xt[p * XS_ + t + 256];
      acc2[0][0] += a0.x * x0;  acc2[1][0] += a0.x * x1;
      acc2[0][1] += a0.y * x0;  acc2[1][1] += a0.y * x1;
      acc2[0][2] += a0.z * x0;  acc2[1][2] += a0.z * x1;
      acc2[0][3] += a0.w * x0;  acc2[1][3] += a0.w * x1;
      acc2[0][4] += a1.x * x0;  acc2[1][4] += a1.x * x1;
      acc2[0][5] += a1.y * x0;  acc2[1][5] += a1.y * x1;
      acc2[0][6] += a1.z * x0;  acc2[1][6] += a1.z * x1;
      acc2[0][7] += a1.w * x0;  acc2[1][7] += a1.w * x1;
    }
  }

  const size_t base = (size_t)(n * NBLK_P + pb) * KV_ * C_;
#pragma unroll
  for (int k = 0; k < KV_; ++k) {
    part_ax[base + k * C_ + t]       = acc2[0][k];
    part_ax[base + k * C_ + t + 256] = acc2[1][k];
  }
  if (t == 0) {
#pragma unroll
    for (int k = 0; k < KV_; ++k)
      asum_part[(n * NBLK_P + pb) * KV_ + k] = asum[k];
  }
}

// ---------------------------------------------------------------------------
// Reducer: sum 16 block-partials, residual vs centers, L2 normalize, write.
// Grid: N*8 blocks (one per (n,k)) of 256 threads.
// ---------------------------------------------------------------------------
__global__ __launch_bounds__(256) void vlad_reduce(
    const float* __restrict__ part_ax, const float* __restrict__ asum_part,
    const float* __restrict__ centers, float* __restrict__ out) {
  __shared__ float sred[4];
  const int n = blockIdx.x >> 3;
  const int k = blockIdx.x & 7;
  const int t = threadIdx.x, lane = t & 63, wv = t >> 6;

  float s0 = 0.f, s1 = 0.f, asv = 0.f;
#pragma unroll
  for (int b = 0; b < NBLK_P; ++b) {
    const size_t base = ((size_t)(n * NBLK_P + b) * KV_ + k) * C_;
    s0  += part_ax[base + t];
    s1  += part_ax[base + t + 256];
    asv += asum_part[(n * NBLK_P + b) * KV_ + k];
  }
  const float r0 = s0 - asv * centers[k * C_ + t];
  const float r1 = s1 - asv * centers[k * C_ + t + 256];

  float ss = r0 * r0 + r1 * r1;
#pragma unroll
  for (int d = 1; d < 64; d <<= 1) ss += __shfl_xor(ss, d, 64);
  if (lane == 0) sred[wv] = ss;
  __syncthreads();
  const float tot = (sred[0] + sred[1]) + (sred[2] + sred[3]);
  const float inv = 1.f / fmaxf(sqrtf(tot), 1e-12f);

  out[(size_t)n * (KV_ * C_) + k * C_ + t]       = r0 * inv;
  out[(size_t)n * (KV_ * C_) + k * C_ + t + 256] = r1 * inv;
}

extern "C" void kernel_launch(void* const* d_in, const int* in_sizes, int n_in,
                              void* d_out, int out_size, void* d_ws, size_t ws_size,
                              hipStream_t stream) {
  const float* x       = (const float*)d_in[0];
  const float* conv_w  = (const float*)d_in[1];
  const float* conv_b  = (const float*)d_in[2];
  const float* centers = (const float*)d_in[3];
  float* out = (float*)d_out;

  float* part_ax   = (float*)d_ws;                                  // 8 MiB
  float* asum_part = part_ax + (size_t)N_ * NBLK_P * KV_ * C_;      // 16 KiB

  hipLaunchKernelGGL(vlad_fused, dim3(N_ * NBLK_P), dim3(256), 0, stream,
                     x, conv_w, conv_b, part_ax, asum_part);
  hipLaunchKernelGGL(vlad_reduce, dim3(N_ * KV_), dim3(256), 0, stream,
                     part_ax, asum_part, centers, out);
}

// Round 4
// 116.238 us; speedup vs baseline: 1.1146x; 1.1146x over previous
//
#include <hip/hip_runtime.h>
#include <math.h>

#define N_    32
#define C_    512
#define P_    1024
#define KG_   10
#define KV_   8
#define PBLK_ 64            // p per block in logits kernel
#define NPB_  (P_ / PBLK_)  // 16
#define PS_   81            // part row stride (17*pl mod 32 -> conflict-free)

// ---------------------------------------------------------------------------
// Kernel A: logits + softmax. Block = (n, 64-p chunk), 512 threads = 8 waves.
// Wave w reduces c in [w*64, (w+1)*64): w[k][c] indices are wave-uniform ->
// scalar-pipe s_loads that never enter the vector-load FIFO. x loads: lane<->p,
// 256 B contiguous per wave-instr. One __syncthreads, one small tail phase.
// Grid: N*16 = 512 blocks -> 16-24 waves/CU.
// ---------------------------------------------------------------------------
__global__ __launch_bounds__(512) void vlad_logits(
    const float* __restrict__ x, const float* __restrict__ w,
    const float* __restrict__ bias, float* __restrict__ a_ws,
    float* __restrict__ asum_blk) {
  __shared__ float part[PBLK_ * PS_];   // 20736 B
  const int t  = threadIdx.x;
  const int pl = t & 63;
  const int cg = __builtin_amdgcn_readfirstlane(threadIdx.x >> 6);  // 0..7
  const int n  = blockIdx.x >> 4;
  const int pb = blockIdx.x & 15;
  const int p0 = pb * PBLK_;

  const float* xp = x + ((size_t)n * C_ + cg * 64) * P_ + p0 + pl;

  float acc[KG_];
#pragma unroll
  for (int k = 0; k < KG_; ++k) acc[k] = 0.f;

#pragma unroll 8
  for (int i = 0; i < 64; ++i) {
    const float xv = xp[(size_t)i * P_];          // coalesced vector load
    const int c = cg * 64 + i;                    // uniform -> s_load for w
#pragma unroll
    for (int k = 0; k < KG_; ++k) acc[k] += xv * w[k * C_ + c];
  }

#pragma unroll
  for (int k = 0; k < KG_; ++k) part[pl * PS_ + cg * KG_ + k] = acc[k];
  __syncthreads();

  if (t < 64) {                                    // wave 0 tail
    float l[KG_];
    float m = -1e30f;
#pragma unroll
    for (int k = 0; k < KG_; ++k) {
      float s = bias[k];
#pragma unroll
      for (int g = 0; g < 8; ++g) s += part[t * PS_ + g * KG_ + k];
      l[k] = s;
      m = fmaxf(m, s);
    }
    float sum = 0.f;
#pragma unroll
    for (int k = 0; k < KG_; ++k) { l[k] = __expf(l[k] - m); sum += l[k]; }
    const float inv = 1.f / sum;
#pragma unroll
    for (int k = 0; k < KV_; ++k) {
      const float a = l[k] * inv;
      a_ws[((size_t)n * KV_ + k) * P_ + p0 + t] = a;   // coalesced
      float s = a;                                     // sum over 64 p (lanes)
      s += __shfl_xor(s, 1, 64);  s += __shfl_xor(s, 2, 64);
      s += __shfl_xor(s, 4, 64);  s += __shfl_xor(s, 8, 64);
      s += __shfl_xor(s, 16, 64); s += __shfl_xor(s, 32, 64);
      if (t == 0) asum_blk[(n * NPB_ + pb) * KV_ + k] = s;
    }
  }
}

// ---------------------------------------------------------------------------
// Kernel B: ax[n][k][c] = sum_p a[n][k][p] * x[n][c][p]. Block = (n, 16-c
// slice) covering ALL p -> writes final ax, no partial buffer. Wave owns 4 c's
// exclusively; lanes<->p via float4 (fully coalesced). x second read is
// L3-hot; a is L2-hot. Grid: N*32 = 1024 blocks of 256 -> 16 waves/CU.
// ---------------------------------------------------------------------------
__global__ __launch_bounds__(256) void vlad_ax(
    const float* __restrict__ x, const float* __restrict__ a_ws,
    float* __restrict__ ax_ws) {
  const int n    = blockIdx.x >> 5;
  const int cb   = blockIdx.x & 31;
  const int lane = threadIdx.x & 63;
  const int wv   = threadIdx.x >> 6;
  const int c0   = cb * 16 + wv * 4;

  const float* ap = a_ws + (size_t)n * KV_ * P_;
  const float* xp = x + (size_t)n * C_ * P_;

  float acc[4][8];
#pragma unroll
  for (int cc = 0; cc < 4; ++cc)
#pragma unroll
    for (int k = 0; k < 8; ++k) acc[cc][k] = 0.f;

#pragma unroll
  for (int i = 0; i < 4; ++i) {
    const int pb = i * 256 + lane * 4;
    float4 a4[8];
#pragma unroll
    for (int k = 0; k < 8; ++k)
      a4[k] = *reinterpret_cast<const float4*>(ap + (size_t)k * P_ + pb);
#pragma unroll
    for (int cc = 0; cc < 4; ++cc) {
      float4 x4 = *reinterpret_cast<const float4*>(xp + (size_t)(c0 + cc) * P_ + pb);
#pragma unroll
      for (int k = 0; k < 8; ++k)
        acc[cc][k] += x4.x * a4[k].x + x4.y * a4[k].y
                    + x4.z * a4[k].z + x4.w * a4[k].w;
    }
  }

  // Pack 32 partials, reduce across 64 lanes with value-splitting butterfly.
  float v[32];
#pragma unroll
  for (int cc = 0; cc < 4; ++cc)
#pragma unroll
    for (int k = 0; k < 8; ++k) v[cc * 8 + k] = acc[cc][k];

  {  // step mask=1, keep 16
    const bool hi = lane & 1;
#pragma unroll
    for (int j = 0; j < 16; ++j) {
      float send = hi ? v[j] : v[j + 16];
      float keep = hi ? v[j + 16] : v[j];
      v[j] = keep + __shfl_xor(send, 1, 64);
    }
  }
  {  // mask=2, keep 8
    const bool hi = lane & 2;
#pragma unroll
    for (int j = 0; j < 8; ++j) {
      float send = hi ? v[j] : v[j + 8];
      float keep = hi ? v[j + 8] : v[j];
      v[j] = keep + __shfl_xor(send, 2, 64);
    }
  }
  {  // mask=4, keep 4
    const bool hi = lane & 4;
#pragma unroll
    for (int j = 0; j < 4; ++j) {
      float send = hi ? v[j] : v[j + 4];
      float keep = hi ? v[j + 4] : v[j];
      v[j] = keep + __shfl_xor(send, 4, 64);
    }
  }
  {  // mask=8, keep 2
    const bool hi = lane & 8;
#pragma unroll
    for (int j = 0; j < 2; ++j) {
      float send = hi ? v[j] : v[j + 2];
      float keep = hi ? v[j + 2] : v[j];
      v[j] = keep + __shfl_xor(send, 8, 64);
    }
  }
  {  // mask=16, keep 1
    const bool hi = lane & 16;
    float send = hi ? v[0] : v[1];
    float keep = hi ? v[1] : v[0];
    v[0] = keep + __shfl_xor(send, 16, 64);
  }
  v[0] += __shfl_xor(v[0], 32, 64);

  if (lane < 32) {
    const int o = ((lane & 1) << 4) | ((lane & 2) << 2) | (lane & 4)
                | (((lane >> 3) & 1) << 1) | ((lane >> 4) & 1);
    const int cc = o >> 3;
    const int k  = o & 7;
    ax_ws[((size_t)n * KV_ + k) * C_ + (c0 + cc)] = v[0];
  }
}

// ---------------------------------------------------------------------------
// Kernel C: asum (sum of 16 block partials), residual vs centers, L2
// normalize, write. Grid: N*8 = 256 blocks of 256.
// ---------------------------------------------------------------------------
__global__ __launch_bounds__(256) void vlad_fin(
    const float* __restrict__ ax_ws, const float* __restrict__ asum_blk,
    const float* __restrict__ centers, float* __restrict__ out) {
  __shared__ float sred[4];
  const int n = blockIdx.x >> 3;
  const int k = blockIdx.x & 7;
  const int t = threadIdx.x, lane = t & 63, wv = t >> 6;

  float asv = 0.f;
#pragma unroll
  for (int pb = 0; pb < NPB_; ++pb)                 // uniform -> s_loads
    asv += asum_blk[(n * NPB_ + pb) * KV_ + k];

  const int c = t * 2;
  const float2 av = *reinterpret_cast<const float2*>(&ax_ws[((size_t)n * KV_ + k) * C_ + c]);
  const float2 ct = *reinterpret_cast<const float2*>(&centers[k * C_ + c]);
  const float r0 = av.x - asv * ct.x;
  const float r1 = av.y - asv * ct.y;

  float ss = r0 * r0 + r1 * r1;
#pragma unroll
  for (int d = 1; d < 64; d <<= 1) ss += __shfl_xor(ss, d, 64);
  if (lane == 0) sred[wv] = ss;
  __syncthreads();
  const float tot = (sred[0] + sred[1]) + (sred[2] + sred[3]);
  const float inv = 1.f / fmaxf(sqrtf(tot), 1e-12f);

  out[(size_t)n * (KV_ * C_) + k * C_ + c]     = r0 * inv;
  out[(size_t)n * (KV_ * C_) + k * C_ + c + 1] = r1 * inv;
}

extern "C" void kernel_launch(void* const* d_in, const int* in_sizes, int n_in,
                              void* d_out, int out_size, void* d_ws, size_t ws_size,
                              hipStream_t stream) {
  const float* x       = (const float*)d_in[0];
  const float* conv_w  = (const float*)d_in[1];
  const float* conv_b  = (const float*)d_in[2];
  const float* centers = (const float*)d_in[3];
  float* out = (float*)d_out;

  float* a_ws     = (float*)d_ws;                        // 1 MiB
  float* ax_ws    = a_ws + (size_t)N_ * KV_ * P_;        // 512 KiB
  float* asum_blk = ax_ws + (size_t)N_ * KV_ * C_;       // 16 KiB

  hipLaunchKernelGGL(vlad_logits, dim3(N_ * NPB_), dim3(512), 0, stream,
                     x, conv_w, conv_b, a_ws, asum_blk);
  hipLaunchKernelGGL(vlad_ax,     dim3(N_ * 32),   dim3(256), 0, stream,
                     x, a_ws, ax_ws);
  hipLaunchKernelGGL(vlad_fin,    dim3(N_ * KV_),  dim3(256), 0, stream,
                     ax_ws, asum_blk, centers, out);
}